// Round 8
// baseline (215.791 us; speedup 1.0000x reference)
//
#include <hip/hip_runtime.h>
#include <math.h>

#define B 8
#define S 2048
#define D_MODEL 512
#define NK 256      // n_kernels (conv out channels / attention feature dim)
#define KSZ 9
#define NC 4096     // n_classes
#define PADW 4
#define SSPLIT 4    // attention s-dimension split
#define CM 64       // conv s-rows per block
#define CW (CM + 8) // staged window rows (72)
#define NSTG (KSZ * 16)                // 144 K-stages: stg = t*16 + h (h = 32-d chunk)
#define NTILES ((S / SSPLIT) / 32)     // 16 x-tiles per attn block

typedef __attribute__((ext_vector_type(8))) short bf16x8;
typedef __attribute__((ext_vector_type(4))) float f32x4;

static __device__ __forceinline__ unsigned short f2bf(float f) {
    unsigned int u = __float_as_uint(f);
    unsigned int r = (u + 0x7fffu + ((u >> 16) & 1u)) >> 16;
    return (unsigned short)r;
}

#define GLOAD_LDS16(g, l) __builtin_amdgcn_global_load_lds( \
    (const __attribute__((address_space(1))) void*)(g),     \
    (__attribute__((address_space(3))) void*)(l), 16, 0, 0)

// ---- fused prep: conv_w -> wtb [stg][k][d32] bf16 (stage-contig 16KB);
// ---- U (pre-scaled by log2e) / F fp32 -> bf16, 4 elems/thread vectorized --
#define PREP_W (KSZ * NK * D_MODEL)
#define PREP_UF (NC * NK)
#define PREP_N (PREP_W + (2 * PREP_UF) / 4)
__global__ __launch_bounds__(256) void prep_all(
    const float* __restrict__ w, unsigned short* __restrict__ wtb,
    const float* __restrict__ U, unsigned short* __restrict__ Ub,
    const float* __restrict__ F, unsigned short* __restrict__ Fb)
{
    const float LOG2E = 1.44269504088896340736f;
    int idx = blockIdx.x * 256 + threadIdx.x;
    if (idx < PREP_W) {
        int dd  = idx & 31;
        int k   = (idx >> 5) & (NK - 1);
        int stg = idx >> 13;              // / (32*NK)
        int t = stg >> 4, h = stg & 15;
        wtb[idx] = f2bf(w[((size_t)k * D_MODEL + h * 32 + dd) * KSZ + t]);
        return;
    }
    idx -= PREP_W;
    if (idx < PREP_UF / 4) {
        float4 v = ((const float4*)U)[idx];
        ushort4 o;
        o.x = f2bf(v.x * LOG2E); o.y = f2bf(v.y * LOG2E);
        o.z = f2bf(v.z * LOG2E); o.w = f2bf(v.w * LOG2E);
        ((ushort4*)Ub)[idx] = o;
        return;
    }
    idx -= PREP_UF / 4;
    if (idx < PREP_UF / 4) {
        float4 v = ((const float4*)F)[idx];
        ushort4 o;
        o.x = f2bf(v.x); o.y = f2bf(v.y);
        o.z = f2bf(v.z); o.w = f2bf(v.w);
        ((ushort4*)Fb)[idx] = o;
    }
}

// ---- embed-gather + MFMA conv1d + bias + tanh -> xf bf16 [b][s][k] --------
// (round-8 proven optimum: window staged once, ONE barrier, depth-3 static
// software pipeline, 8 waves M64xN32, stage-contiguous weight stream.)
__global__ __launch_bounds__(512, 2) void conv_mfma(
    const int* __restrict__ text, const float* __restrict__ emb,
    const unsigned short* __restrict__ wtb, const float* __restrict__ bias,
    unsigned short* __restrict__ xf)
{
    __shared__ unsigned short xs[CW * D_MODEL];   // 73,728 B
    const int b  = blockIdx.x >> 5;               // S/CM = 32 s-blocks
    const int s0 = (blockIdx.x & 31) * CM;
    const int tid = threadIdx.x;

    for (int u = tid; u < CW * 64; u += 512) {
        int row = u >> 6, c = u & 63;             // c = logical 16B chunk
        int gs = s0 + row - PADW;
        float4 v0 = make_float4(0.f, 0.f, 0.f, 0.f), v1 = v0;
        if (gs >= 0 && gs < S) {
            int tok = text[b * S + gs];
            const float4* e4 = (const float4*)(emb + (size_t)tok * D_MODEL + c * 8);
            v0 = e4[0]; v1 = e4[1];
        }
        union { bf16x8 v; unsigned short us[8]; } pk;
        pk.us[0] = f2bf(v0.x); pk.us[1] = f2bf(v0.y);
        pk.us[2] = f2bf(v0.z); pk.us[3] = f2bf(v0.w);
        pk.us[4] = f2bf(v1.x); pk.us[5] = f2bf(v1.y);
        pk.us[6] = f2bf(v1.z); pk.us[7] = f2bf(v1.w);
        int phys = c ^ (row & 7);
        *(bf16x8*)(xs + row * D_MODEL + phys * 8) = pk.v;
    }
    __syncthreads();                              // the ONLY barrier

    const int wv   = tid >> 6;                    // 0..7
    const int lane = tid & 63;
    const int cl   = lane & 15;
    const int quad = lane >> 4;
    const int n0   = wv * 32;                     // 8 waves cover 256 channels

    bf16x8 A0[4], A1[4], A2[4], B0[2], B1[2], B2[2];
    f32x4 acc[4][2] = {};

    #define LDB(BB, stg)                                                      \
        {                                                                     \
            const unsigned short* wp = wtb + (size_t)(stg) * (NK * 32)        \
                                       + (n0 + cl) * 32 + quad * 8;           \
            BB[0] = *(const bf16x8*)(wp);                                     \
            BB[1] = *(const bf16x8*)(wp + 16 * 32);                           \
        }
    #define LDA(AA, stg)                                                      \
        {                                                                     \
            int t_ = (stg) >> 4, h_ = (stg) & 15;                             \
            _Pragma("unroll")                                                 \
            for (int ms = 0; ms < 4; ms++) {                                  \
                int row = cl + ms * 16 + t_;                                  \
                int ph  = (h_ * 4 + quad) ^ (row & 7);                        \
                AA[ms] = *(const bf16x8*)(xs + row * D_MODEL + ph * 8);       \
            }                                                                 \
        }
    #define FENCE asm volatile("" ::: "memory");
    #define DOMFMA(AA, BB)                                                    \
        _Pragma("unroll")                                                     \
        for (int ms = 0; ms < 4; ms++) {                                      \
            acc[ms][0] = __builtin_amdgcn_mfma_f32_16x16x32_bf16(AA[ms], BB[0], acc[ms][0], 0, 0, 0); \
            acc[ms][1] = __builtin_amdgcn_mfma_f32_16x16x32_bf16(AA[ms], BB[1], acc[ms][1], 0, 0, 0); \
        }

    LDB(B0, 0) LDA(A0, 0) LDB(B1, 1) LDA(A1, 1) LDB(B2, 2) LDA(A2, 2) FENCE

    for (int ss = 0; ss < NSTG; ss += 3) {        // 48 iters
        DOMFMA(A0, B0)
        if (ss + 3 < NSTG) { LDB(B0, ss + 3) LDA(A0, ss + 3) FENCE }
        DOMFMA(A1, B1)
        if (ss + 4 < NSTG) { LDB(B1, ss + 4) LDA(A1, ss + 4) FENCE }
        DOMFMA(A2, B2)
        if (ss + 5 < NSTG) { LDB(B2, ss + 5) LDA(A2, ss + 5) FENCE }
    }

    #pragma unroll
    for (int ns = 0; ns < 2; ns++) {
        const int k = n0 + ns * 16 + cl;
        const float bk = bias[k];
        #pragma unroll
        for (int ms = 0; ms < 4; ms++) {
            #pragma unroll
            for (int r = 0; r < 4; r++) {
                int s = s0 + ms * 16 + quad * 4 + r;
                float v = acc[ms][ns][r] + bk;
                float e = __expf(2.f * v);
                float th = 1.f - 2.f / (e + 1.f); // tanh(v)
                xf[((size_t)b * S + s) * NK + k] = f2bf(th);
            }
        }
    }
}

// -------- MFMA attention: max-free softmax, bf16 U/F tables ----------------
// r6 post-mortem: VGPR_Count=68 < 64 (tables) + 32 (acc) => the compiler has
// been REMATERIALIZING the uf/ff global loads inside the tile loop in every
// version (r0: 108 vs ~190 needed; r5: 60; r6: 68). Per tile that adds 16
// global loads/wave AND compiler vmcnt waits for them — vmcnt retires in
// order, so those waits drain the STAGE prefetch queue too, defeating r6's
// counted-vmcnt pipeline. This round (single variable on r6): PIN the table
// fragments with asm "+v" after a batched load — asm-defined values cannot
// be rematerialized, forcing residency (~95-110 VGPR, still 3 blocks/CU).
// Keeps r6's triple-buffer + vmcnt(4) + raw s_barrier schedule unchanged.
// r1 lesson: LDS staging is load-bearing. r2 lesson: natural block order
// already gives U/F XCD locality.
#define WAITVM4 asm volatile("s_waitcnt vmcnt(4)" ::: "memory")
#define WAITVM0 asm volatile("s_waitcnt vmcnt(0)" ::: "memory")
#define KEEP(x) asm volatile("" : "+v"(x))
__global__ __launch_bounds__(256, 3) void attn_mfma(
    const unsigned short* __restrict__ xf, const unsigned short* __restrict__ Ub,
    const unsigned short* __restrict__ Fb, float* __restrict__ pl,
    float* __restrict__ pg)
{
    __shared__ unsigned short xsa[3 * 32 * NK];   // 3 x 16 KB
    const int b    = blockIdx.z;
    const int sp   = blockIdx.y;
    const int tid  = threadIdx.x;
    const int wv   = tid >> 6;
    const int lane = tid & 63;
    const int cl   = lane & 15;
    const int quad = lane >> 4;
    const int c0   = blockIdx.x * 64 + wv * 16;   // 16 classes per wave
    const int wvu  = __builtin_amdgcn_readfirstlane(wv);

    bf16x8 uf[8], ff[8];
    {
        const unsigned short* up = Ub + (size_t)(c0 + cl) * NK + quad * 8;
        const unsigned short* fp = Fb + (size_t)(c0 + cl) * NK + quad * 8;
        #pragma unroll
        for (int kk = 0; kk < 8; kk++) {
            uf[kk] = *(const bf16x8*)(up + kk * 32);
            ff[kk] = *(const bf16x8*)(fp + kk * 32);
        }
        // Pin AFTER all loads are issued: asm-defined values cannot be
        // rematerialized; regalloc must keep them resident for the kernel.
        #pragma unroll
        for (int kk = 0; kk < 8; kk++) { KEEP(uf[kk]); KEEP(ff[kk]); }
    }

    const int sbeg = sp * (S / SSPLIT);
    const unsigned short* xb = xf + ((size_t)b * S + sbeg) * NK;

    #define STAGE(bb, t)                                                      \
        {                                                                     \
            _Pragma("unroll")                                                 \
            for (int j = 0; j < 4; j++) {                                     \
                int C = j * 256 + tid;                                        \
                int r = C >> 5, p = C & 31;                                   \
                int jl = p ^ (r & 7);                                         \
                const unsigned short* src = xb + (size_t)((t) * 32 + r) * NK + jl * 8; \
                unsigned short* dst = xsa + (size_t)(bb) * 8192 + j * 2048 + wvu * 512; \
                GLOAD_LDS16(src, dst);                                        \
            }                                                                 \
        }

    STAGE(0, 0)
    STAGE(1, 1)

    float l = 0.f, G = 0.f;
    const int swz = cl & 7;

    int cur = 0, nx2 = 2;                         // buf of tile t / tile t+2
    for (int t = 0; t < NTILES; t++) {
        if (t + 1 < NTILES) { WAITVM4; } else { WAITVM0; }
        __builtin_amdgcn_s_barrier();
        if (t + 2 < NTILES) STAGE(nx2, t + 2)

        const unsigned short* bs = xsa + cur * 8192;
        f32x4 sa[2] = {}, ga[2] = {};             // [rowgrp]
        #pragma unroll
        for (int kk = 0; kk < 8; kk++) {
            int p0 = (quad + 4 * kk) ^ swz;
            bf16x8 a0 = *(const bf16x8*)(bs + cl * NK + p0 * 8);
            bf16x8 a1 = *(const bf16x8*)(bs + (16 + cl) * NK + p0 * 8);
            sa[0] = __builtin_amdgcn_mfma_f32_16x16x32_bf16(a0, uf[kk], sa[0], 0, 0, 0);
            ga[0] = __builtin_amdgcn_mfma_f32_16x16x32_bf16(a0, ff[kk], ga[0], 0, 0, 0);
            sa[1] = __builtin_amdgcn_mfma_f32_16x16x32_bf16(a1, uf[kk], sa[1], 0, 0, 0);
            ga[1] = __builtin_amdgcn_mfma_f32_16x16x32_bf16(a1, ff[kk], ga[1], 0, 0, 0);
        }

        // max-free softmax accumulation (straight-line)
        #pragma unroll
        for (int r = 0; r < 4; r++) {
            float e0 = __builtin_amdgcn_exp2f(sa[0][r]);
            float e1 = __builtin_amdgcn_exp2f(sa[1][r]);
            l += e0 + e1;
            G += e0 * ga[0][r] + e1 * ga[1][r];
        }

        cur = (cur == 2) ? 0 : cur + 1;
        nx2 = (nx2 == 2) ? 0 : nx2 + 1;
    }

    l += __shfl_xor(l, 16); l += __shfl_xor(l, 32);
    G += __shfl_xor(G, 16); G += __shfl_xor(G, 32);
    if (lane < 16) {
        size_t idx = ((size_t)b * SSPLIT + sp) * NC + c0 + lane;
        pl[idx] = l; pg[idx] = G;
    }
}

// -------- combine S-split partials + bias -> y [b][c] ----------------------
__global__ __launch_bounds__(256) void combine_kernel(
    const float* __restrict__ pl, const float* __restrict__ pg,
    const float* __restrict__ fb, float* __restrict__ out)
{
    int idx = blockIdx.x * 256 + threadIdx.x;     // over B*NC
    if (idx >= B * NC) return;
    int b = idx / NC, c = idx % NC;
    float l = 0.f, g = 0.f;
    #pragma unroll
    for (int sp = 0; sp < SSPLIT; sp++) {
        size_t i = ((size_t)b * SSPLIT + sp) * NC + c;
        l += pl[i];
        g += pg[i];
    }
    out[idx] = g / l + fb[c];
}

extern "C" void kernel_launch(void* const* d_in, const int* in_sizes, int n_in,
                              void* d_out, int out_size, void* d_ws, size_t ws_size,
                              hipStream_t stream) {
    const int*   text   = (const int*)  d_in[0];
    const float* emb    = (const float*)d_in[1];
    const float* conv_w = (const float*)d_in[2];
    const float* conv_b = (const float*)d_in[3];
    const float* U_w    = (const float*)d_in[4];
    const float* F_w    = (const float*)d_in[5];
    const float* f_b    = (const float*)d_in[6];
    float* out = (float*)d_out;

    char* ws = (char*)d_ws;
    unsigned short* xf  = (unsigned short*)ws; ws += (size_t)B * S * NK * 2;
    unsigned short* wtb = (unsigned short*)ws; ws += (size_t)KSZ * NK * D_MODEL * 2;
    unsigned short* Ub  = (unsigned short*)ws; ws += (size_t)NC * NK * 2;
    unsigned short* Fb  = (unsigned short*)ws; ws += (size_t)NC * NK * 2;
    float* pl = (float*)ws; ws += (size_t)SSPLIT * B * NC * 4;
    float* pg = (float*)ws; ws += (size_t)SSPLIT * B * NC * 4;

    prep_all<<<dim3((PREP_N + 255) / 256), 256, 0, stream>>>(conv_w, wtb, U_w, Ub, F_w, Fb);
    conv_mfma<<<dim3(B * S / CM), 512, 0, stream>>>(text, emb, wtb, conv_b, xf);
    attn_mfma<<<dim3(NC / 64, SSPLIT, B), 256, 0, stream>>>(xf, Ub, Fb, pl, pg);
    combine_kernel<<<dim3((B * NC + 255) / 256), 256, 0, stream>>>(pl, pg, f_b, out);
}

// Round 9
// 214.099 us; speedup vs baseline: 1.0079x; 1.0079x over previous
//
#include <hip/hip_runtime.h>
#include <math.h>

#define B 8
#define S 2048
#define D_MODEL 512
#define NK 256      // n_kernels (conv out channels / attention feature dim)
#define KSZ 9
#define NC 4096     // n_classes
#define PADW 4
#define SSPLIT 4    // attention s-dimension split
#define CM 64       // conv s-rows per block
#define CW (CM + 8) // staged window rows (72)
#define NSTG (KSZ * 16)                // 144 K-stages: stg = t*16 + h (h = 32-d chunk)
#define NTILES ((S / SSPLIT) / 32)     // 16 x-tiles per attn block

typedef __attribute__((ext_vector_type(8))) short bf16x8;
typedef __attribute__((ext_vector_type(4))) float f32x4;

static __device__ __forceinline__ unsigned short f2bf(float f) {
    unsigned int u = __float_as_uint(f);
    unsigned int r = (u + 0x7fffu + ((u >> 16) & 1u)) >> 16;
    return (unsigned short)r;
}

#define GLOAD_LDS16(g, l) __builtin_amdgcn_global_load_lds( \
    (const __attribute__((address_space(1))) void*)(g),     \
    (__attribute__((address_space(3))) void*)(l), 16, 0, 0)

// ---- fused prep: conv_w -> wtb [stg][k][d32] bf16 (stage-contig 16KB);
// ---- U (pre-scaled by log2e) / F fp32 -> bf16, 4 elems/thread vectorized --
#define PREP_W (KSZ * NK * D_MODEL)
#define PREP_UF (NC * NK)
#define PREP_N (PREP_W + (2 * PREP_UF) / 4)
__global__ __launch_bounds__(256) void prep_all(
    const float* __restrict__ w, unsigned short* __restrict__ wtb,
    const float* __restrict__ U, unsigned short* __restrict__ Ub,
    const float* __restrict__ F, unsigned short* __restrict__ Fb)
{
    const float LOG2E = 1.44269504088896340736f;
    int idx = blockIdx.x * 256 + threadIdx.x;
    if (idx < PREP_W) {
        int dd  = idx & 31;
        int k   = (idx >> 5) & (NK - 1);
        int stg = idx >> 13;              // / (32*NK)
        int t = stg >> 4, h = stg & 15;
        wtb[idx] = f2bf(w[((size_t)k * D_MODEL + h * 32 + dd) * KSZ + t]);
        return;
    }
    idx -= PREP_W;
    if (idx < PREP_UF / 4) {
        float4 v = ((const float4*)U)[idx];
        ushort4 o;
        o.x = f2bf(v.x * LOG2E); o.y = f2bf(v.y * LOG2E);
        o.z = f2bf(v.z * LOG2E); o.w = f2bf(v.w * LOG2E);
        ((ushort4*)Ub)[idx] = o;
        return;
    }
    idx -= PREP_UF / 4;
    if (idx < PREP_UF / 4) {
        float4 v = ((const float4*)F)[idx];
        ushort4 o;
        o.x = f2bf(v.x); o.y = f2bf(v.y);
        o.z = f2bf(v.z); o.w = f2bf(v.w);
        ((ushort4*)Fb)[idx] = o;
    }
}

// ---- embed-gather + MFMA conv1d + bias + tanh -> xf bf16 [b][s][k] --------
// (round-8 proven optimum: window staged once, ONE barrier, depth-3 static
// software pipeline, 8 waves M64xN32, stage-contiguous weight stream.)
__global__ __launch_bounds__(512, 2) void conv_mfma(
    const int* __restrict__ text, const float* __restrict__ emb,
    const unsigned short* __restrict__ wtb, const float* __restrict__ bias,
    unsigned short* __restrict__ xf)
{
    __shared__ unsigned short xs[CW * D_MODEL];   // 73,728 B
    const int b  = blockIdx.x >> 5;               // S/CM = 32 s-blocks
    const int s0 = (blockIdx.x & 31) * CM;
    const int tid = threadIdx.x;

    for (int u = tid; u < CW * 64; u += 512) {
        int row = u >> 6, c = u & 63;             // c = logical 16B chunk
        int gs = s0 + row - PADW;
        float4 v0 = make_float4(0.f, 0.f, 0.f, 0.f), v1 = v0;
        if (gs >= 0 && gs < S) {
            int tok = text[b * S + gs];
            const float4* e4 = (const float4*)(emb + (size_t)tok * D_MODEL + c * 8);
            v0 = e4[0]; v1 = e4[1];
        }
        union { bf16x8 v; unsigned short us[8]; } pk;
        pk.us[0] = f2bf(v0.x); pk.us[1] = f2bf(v0.y);
        pk.us[2] = f2bf(v0.z); pk.us[3] = f2bf(v0.w);
        pk.us[4] = f2bf(v1.x); pk.us[5] = f2bf(v1.y);
        pk.us[6] = f2bf(v1.z); pk.us[7] = f2bf(v1.w);
        int phys = c ^ (row & 7);
        *(bf16x8*)(xs + row * D_MODEL + phys * 8) = pk.v;
    }
    __syncthreads();                              // the ONLY barrier

    const int wv   = tid >> 6;                    // 0..7
    const int lane = tid & 63;
    const int cl   = lane & 15;
    const int quad = lane >> 4;
    const int n0   = wv * 32;                     // 8 waves cover 256 channels

    bf16x8 A0[4], A1[4], A2[4], B0[2], B1[2], B2[2];
    f32x4 acc[4][2] = {};

    #define LDB(BB, stg)                                                      \
        {                                                                     \
            const unsigned short* wp = wtb + (size_t)(stg) * (NK * 32)        \
                                       + (n0 + cl) * 32 + quad * 8;           \
            BB[0] = *(const bf16x8*)(wp);                                     \
            BB[1] = *(const bf16x8*)(wp + 16 * 32);                           \
        }
    #define LDA(AA, stg)                                                      \
        {                                                                     \
            int t_ = (stg) >> 4, h_ = (stg) & 15;                             \
            _Pragma("unroll")                                                 \
            for (int ms = 0; ms < 4; ms++) {                                  \
                int row = cl + ms * 16 + t_;                                  \
                int ph  = (h_ * 4 + quad) ^ (row & 7);                        \
                AA[ms] = *(const bf16x8*)(xs + row * D_MODEL + ph * 8);       \
            }                                                                 \
        }
    #define FENCE asm volatile("" ::: "memory");
    #define DOMFMA(AA, BB)                                                    \
        _Pragma("unroll")                                                     \
        for (int ms = 0; ms < 4; ms++) {                                      \
            acc[ms][0] = __builtin_amdgcn_mfma_f32_16x16x32_bf16(AA[ms], BB[0], acc[ms][0], 0, 0, 0); \
            acc[ms][1] = __builtin_amdgcn_mfma_f32_16x16x32_bf16(AA[ms], BB[1], acc[ms][1], 0, 0, 0); \
        }

    LDB(B0, 0) LDA(A0, 0) LDB(B1, 1) LDA(A1, 1) LDB(B2, 2) LDA(A2, 2) FENCE

    for (int ss = 0; ss < NSTG; ss += 3) {        // 48 iters
        DOMFMA(A0, B0)
        if (ss + 3 < NSTG) { LDB(B0, ss + 3) LDA(A0, ss + 3) FENCE }
        DOMFMA(A1, B1)
        if (ss + 4 < NSTG) { LDB(B1, ss + 4) LDA(A1, ss + 4) FENCE }
        DOMFMA(A2, B2)
        if (ss + 5 < NSTG) { LDB(B2, ss + 5) LDA(A2, ss + 5) FENCE }
    }

    #pragma unroll
    for (int ns = 0; ns < 2; ns++) {
        const int k = n0 + ns * 16 + cl;
        const float bk = bias[k];
        #pragma unroll
        for (int ms = 0; ms < 4; ms++) {
            #pragma unroll
            for (int r = 0; r < 4; r++) {
                int s = s0 + ms * 16 + quad * 4 + r;
                float v = acc[ms][ns][r] + bk;
                float e = __expf(2.f * v);
                float th = 1.f - 2.f / (e + 1.f); // tanh(v)
                xf[((size_t)b * S + s) * NK + k] = f2bf(th);
            }
        }
    }
}

// -------- MFMA attention: max-free softmax, bf16 U/F tables ----------------
// r8 post-mortem: KEEP pin was a no-op (VGPR stuck 68; uf/ff live in AGPRs —
// unified file, counter excludes AGPRs; no remat ever existed). Corrected
// MFMA floor: ~33us/CU (4.85cyc is per-CU); at 68.8us we're 2.1x floor with
// MFMA 42% + VALU 27%. VALU decomposition: softmax ~7%, the other ~20% is
// PER-TILE ADDRESS ARITHMETIC (16 ds_read addr recomputes, staging idx math,
// cur/nx2 ternaries). This round (one variable): full unroll of the 16-tile
// loop (buf = t%3 compile-time) + 2-base-pointer immediate-offset reads:
// ((quad+4kk)^swz)*16 == 128*(kk>>1) + ((quad+4(kk&1))^swz)*16, so all 48
// read variants are pE/pO + imm (<64K). Staging src/dst hoisted. Schedule
// (triple buffer, vmcnt(4), raw s_barrier) unchanged from r6.
// r1: LDS staging load-bearing. r2: natural order has U/F XCD locality.
#define WAITVM4 asm volatile("s_waitcnt vmcnt(4)" ::: "memory")
#define WAITVM0 asm volatile("s_waitcnt vmcnt(0)" ::: "memory")
__global__ __launch_bounds__(256, 3) void attn_mfma(
    const unsigned short* __restrict__ xf, const unsigned short* __restrict__ Ub,
    const unsigned short* __restrict__ Fb, float* __restrict__ pl,
    float* __restrict__ pg)
{
    __shared__ unsigned short xsa[3 * 32 * NK];   // 3 x 16 KB
    const int b    = blockIdx.z;
    const int sp   = blockIdx.y;
    const int tid  = threadIdx.x;
    const int wv   = tid >> 6;
    const int lane = tid & 63;
    const int cl   = lane & 15;
    const int quad = lane >> 4;
    const int c0   = blockIdx.x * 64 + wv * 16;   // 16 classes per wave
    const int wvu  = __builtin_amdgcn_readfirstlane(wv);

    bf16x8 uf[8], ff[8];
    {
        const unsigned short* up = Ub + (size_t)(c0 + cl) * NK + quad * 8;
        const unsigned short* fp = Fb + (size_t)(c0 + cl) * NK + quad * 8;
        #pragma unroll
        for (int kk = 0; kk < 8; kk++) {
            uf[kk] = *(const bf16x8*)(up + kk * 32);
            ff[kk] = *(const bf16x8*)(fp + kk * 32);
        }
    }

    const int sbeg = sp * (S / SSPLIT);
    const unsigned short* xb = xf + ((size_t)b * S + sbeg) * NK;

    // hoisted staging pointers (loop-invariant; only t*32*NK varies)
    const unsigned short* ssrc[4];
    unsigned short* sdst[4];
    #pragma unroll
    for (int j = 0; j < 4; j++) {
        int C = j * 256 + tid;
        int r = C >> 5, p = C & 31;
        int jl = p ^ (r & 7);
        ssrc[j] = xb + (size_t)r * NK + jl * 8;
        sdst[j] = xsa + j * 2048 + wvu * 512;
    }

    #define STAGE(bb, t)                                                      \
        {                                                                     \
            _Pragma("unroll")                                                 \
            for (int j = 0; j < 4; j++)                                       \
                GLOAD_LDS16(ssrc[j] + (t) * (32 * NK), sdst[j] + (bb) * 8192);\
        }

    STAGE(0, 0)
    STAGE(1, 1)

    const int swz = cl & 7;
    // two read base pointers; everything else is compile-time imm offsets
    const unsigned short* pE = xsa + cl * NK + (quad ^ swz) * 8;
    const unsigned short* pO = xsa + cl * NK + ((quad + 4) ^ swz) * 8;

    float l = 0.f, G = 0.f;

    #pragma unroll
    for (int t = 0; t < NTILES; t++) {            // fully unrolled: buf static
        if (t + 1 < NTILES) { WAITVM4; } else { WAITVM0; }
        __builtin_amdgcn_s_barrier();
        if (t + 2 < NTILES) STAGE((t + 2) % 3, t + 2)

        const int buf = t % 3;                    // compile-time after unroll
        f32x4 sa[2] = {}, ga[2] = {};             // [rowgrp]
        #pragma unroll
        for (int kk = 0; kk < 8; kk++) {
            const unsigned short* pp = (kk & 1) ? pO : pE;
            const int eo = buf * 8192 + (kk >> 1) * 64;
            bf16x8 a0 = *(const bf16x8*)(pp + eo);
            bf16x8 a1 = *(const bf16x8*)(pp + eo + 16 * NK);
            sa[0] = __builtin_amdgcn_mfma_f32_16x16x32_bf16(a0, uf[kk], sa[0], 0, 0, 0);
            ga[0] = __builtin_amdgcn_mfma_f32_16x16x32_bf16(a0, ff[kk], ga[0], 0, 0, 0);
            sa[1] = __builtin_amdgcn_mfma_f32_16x16x32_bf16(a1, uf[kk], sa[1], 0, 0, 0);
            ga[1] = __builtin_amdgcn_mfma_f32_16x16x32_bf16(a1, ff[kk], ga[1], 0, 0, 0);
        }

        // max-free softmax accumulation (straight-line)
        #pragma unroll
        for (int r = 0; r < 4; r++) {
            float e0 = __builtin_amdgcn_exp2f(sa[0][r]);
            float e1 = __builtin_amdgcn_exp2f(sa[1][r]);
            l += e0 + e1;
            G += e0 * ga[0][r] + e1 * ga[1][r];
        }
    }

    l += __shfl_xor(l, 16); l += __shfl_xor(l, 32);
    G += __shfl_xor(G, 16); G += __shfl_xor(G, 32);
    if (lane < 16) {
        size_t idx = ((size_t)b * SSPLIT + sp) * NC + c0 + lane;
        pl[idx] = l; pg[idx] = G;
    }
}

// -------- combine S-split partials + bias -> y [b][c] ----------------------
__global__ __launch_bounds__(256) void combine_kernel(
    const float* __restrict__ pl, const float* __restrict__ pg,
    const float* __restrict__ fb, float* __restrict__ out)
{
    int idx = blockIdx.x * 256 + threadIdx.x;     // over B*NC
    if (idx >= B * NC) return;
    int b = idx / NC, c = idx % NC;
    float l = 0.f, g = 0.f;
    #pragma unroll
    for (int sp = 0; sp < SSPLIT; sp++) {
        size_t i = ((size_t)b * SSPLIT + sp) * NC + c;
        l += pl[i];
        g += pg[i];
    }
    out[idx] = g / l + fb[c];
}

extern "C" void kernel_launch(void* const* d_in, const int* in_sizes, int n_in,
                              void* d_out, int out_size, void* d_ws, size_t ws_size,
                              hipStream_t stream) {
    const int*   text   = (const int*)  d_in[0];
    const float* emb    = (const float*)d_in[1];
    const float* conv_w = (const float*)d_in[2];
    const float* conv_b = (const float*)d_in[3];
    const float* U_w    = (const float*)d_in[4];
    const float* F_w    = (const float*)d_in[5];
    const float* f_b    = (const float*)d_in[6];
    float* out = (float*)d_out;

    char* ws = (char*)d_ws;
    unsigned short* xf  = (unsigned short*)ws; ws += (size_t)B * S * NK * 2;
    unsigned short* wtb = (unsigned short*)ws; ws += (size_t)KSZ * NK * D_MODEL * 2;
    unsigned short* Ub  = (unsigned short*)ws; ws += (size_t)NC * NK * 2;
    unsigned short* Fb  = (unsigned short*)ws; ws += (size_t)NC * NK * 2;
    float* pl = (float*)ws; ws += (size_t)SSPLIT * B * NC * 4;
    float* pg = (float*)ws; ws += (size_t)SSPLIT * B * NC * 4;

    prep_all<<<dim3((PREP_N + 255) / 256), 256, 0, stream>>>(conv_w, wtb, U_w, Ub, F_w, Fb);
    conv_mfma<<<dim3(B * S / CM), 512, 0, stream>>>(text, emb, wtb, conv_b, xf);
    attn_mfma<<<dim3(NC / 64, SSPLIT, B), 256, 0, stream>>>(xf, Ub, Fb, pl, pg);
    combine_kernel<<<dim3((B * NC + 255) / 256), 256, 0, stream>>>(pl, pg, f_b, out);
}

// Round 10
// 213.214 us; speedup vs baseline: 1.0121x; 1.0042x over previous
//
#include <hip/hip_runtime.h>
#include <math.h>

#define B 8
#define S 2048
#define D_MODEL 512
#define NK 256      // n_kernels (conv out channels / attention feature dim)
#define KSZ 9
#define NC 4096     // n_classes
#define PADW 4
#define SSPLIT 4    // attention s-dimension split
#define CM 64       // conv s-rows per block
#define CW (CM + 8) // staged window rows (72)
#define NSTG (KSZ * 16)                // 144 K-stages: stg = t*16 + h (h = 32-d chunk)
#define NTILES ((S / SSPLIT) / 32)     // 16 x-tiles per attn block

typedef __attribute__((ext_vector_type(8))) short bf16x8;
typedef __attribute__((ext_vector_type(4))) float f32x4;
typedef __attribute__((ext_vector_type(16))) float f32x16;

static __device__ __forceinline__ unsigned short f2bf(float f) {
    unsigned int u = __float_as_uint(f);
    unsigned int r = (u + 0x7fffu + ((u >> 16) & 1u)) >> 16;
    return (unsigned short)r;
}

#define GLOAD_LDS16(g, l) __builtin_amdgcn_global_load_lds( \
    (const __attribute__((address_space(1))) void*)(g),     \
    (__attribute__((address_space(3))) void*)(l), 16, 0, 0)

// ---- fused prep: conv_w -> wtb [stg][k][d32] bf16 (stage-contig 16KB);
// ---- U (pre-scaled by log2e) / F fp32 -> bf16, 4 elems/thread vectorized --
#define PREP_W (KSZ * NK * D_MODEL)
#define PREP_UF (NC * NK)
#define PREP_N (PREP_W + (2 * PREP_UF) / 4)
__global__ __launch_bounds__(256) void prep_all(
    const float* __restrict__ w, unsigned short* __restrict__ wtb,
    const float* __restrict__ U, unsigned short* __restrict__ Ub,
    const float* __restrict__ F, unsigned short* __restrict__ Fb)
{
    const float LOG2E = 1.44269504088896340736f;
    int idx = blockIdx.x * 256 + threadIdx.x;
    if (idx < PREP_W) {
        int dd  = idx & 31;
        int k   = (idx >> 5) & (NK - 1);
        int stg = idx >> 13;              // / (32*NK)
        int t = stg >> 4, h = stg & 15;
        wtb[idx] = f2bf(w[((size_t)k * D_MODEL + h * 32 + dd) * KSZ + t]);
        return;
    }
    idx -= PREP_W;
    if (idx < PREP_UF / 4) {
        float4 v = ((const float4*)U)[idx];
        ushort4 o;
        o.x = f2bf(v.x * LOG2E); o.y = f2bf(v.y * LOG2E);
        o.z = f2bf(v.z * LOG2E); o.w = f2bf(v.w * LOG2E);
        ((ushort4*)Ub)[idx] = o;
        return;
    }
    idx -= PREP_UF / 4;
    if (idx < PREP_UF / 4) {
        float4 v = ((const float4*)F)[idx];
        ushort4 o;
        o.x = f2bf(v.x); o.y = f2bf(v.y);
        o.z = f2bf(v.z); o.w = f2bf(v.w);
        ((ushort4*)Fb)[idx] = o;
    }
}

// ---- embed-gather + MFMA conv1d + bias + tanh -> xf bf16 [b][s][k] --------
// (round-8 proven optimum: window staged once, ONE barrier, depth-3 static
// software pipeline, 8 waves M64xN32, stage-contiguous weight stream.)
__global__ __launch_bounds__(512, 2) void conv_mfma(
    const int* __restrict__ text, const float* __restrict__ emb,
    const unsigned short* __restrict__ wtb, const float* __restrict__ bias,
    unsigned short* __restrict__ xf)
{
    __shared__ unsigned short xs[CW * D_MODEL];   // 73,728 B
    const int b  = blockIdx.x >> 5;               // S/CM = 32 s-blocks
    const int s0 = (blockIdx.x & 31) * CM;
    const int tid = threadIdx.x;

    for (int u = tid; u < CW * 64; u += 512) {
        int row = u >> 6, c = u & 63;             // c = logical 16B chunk
        int gs = s0 + row - PADW;
        float4 v0 = make_float4(0.f, 0.f, 0.f, 0.f), v1 = v0;
        if (gs >= 0 && gs < S) {
            int tok = text[b * S + gs];
            const float4* e4 = (const float4*)(emb + (size_t)tok * D_MODEL + c * 8);
            v0 = e4[0]; v1 = e4[1];
        }
        union { bf16x8 v; unsigned short us[8]; } pk;
        pk.us[0] = f2bf(v0.x); pk.us[1] = f2bf(v0.y);
        pk.us[2] = f2bf(v0.z); pk.us[3] = f2bf(v0.w);
        pk.us[4] = f2bf(v1.x); pk.us[5] = f2bf(v1.y);
        pk.us[6] = f2bf(v1.z); pk.us[7] = f2bf(v1.w);
        int phys = c ^ (row & 7);
        *(bf16x8*)(xs + row * D_MODEL + phys * 8) = pk.v;
    }
    __syncthreads();                              // the ONLY barrier

    const int wv   = tid >> 6;                    // 0..7
    const int lane = tid & 63;
    const int cl   = lane & 15;
    const int quad = lane >> 4;
    const int n0   = wv * 32;                     // 8 waves cover 256 channels

    bf16x8 A0[4], A1[4], A2[4], B0[2], B1[2], B2[2];
    f32x4 acc[4][2] = {};

    #define LDB(BB, stg)                                                      \
        {                                                                     \
            const unsigned short* wp = wtb + (size_t)(stg) * (NK * 32)        \
                                       + (n0 + cl) * 32 + quad * 8;           \
            BB[0] = *(const bf16x8*)(wp);                                     \
            BB[1] = *(const bf16x8*)(wp + 16 * 32);                           \
        }
    #define LDA(AA, stg)                                                      \
        {                                                                     \
            int t_ = (stg) >> 4, h_ = (stg) & 15;                             \
            _Pragma("unroll")                                                 \
            for (int ms = 0; ms < 4; ms++) {                                  \
                int row = cl + ms * 16 + t_;                                  \
                int ph  = (h_ * 4 + quad) ^ (row & 7);                        \
                AA[ms] = *(const bf16x8*)(xs + row * D_MODEL + ph * 8);       \
            }                                                                 \
        }
    #define FENCE asm volatile("" ::: "memory");
    #define DOMFMA(AA, BB)                                                    \
        _Pragma("unroll")                                                     \
        for (int ms = 0; ms < 4; ms++) {                                      \
            acc[ms][0] = __builtin_amdgcn_mfma_f32_16x16x32_bf16(AA[ms], BB[0], acc[ms][0], 0, 0, 0); \
            acc[ms][1] = __builtin_amdgcn_mfma_f32_16x16x32_bf16(AA[ms], BB[1], acc[ms][1], 0, 0, 0); \
        }

    LDB(B0, 0) LDA(A0, 0) LDB(B1, 1) LDA(A1, 1) LDB(B2, 2) LDA(A2, 2) FENCE

    for (int ss = 0; ss < NSTG; ss += 3) {        // 48 iters
        DOMFMA(A0, B0)
        if (ss + 3 < NSTG) { LDB(B0, ss + 3) LDA(A0, ss + 3) FENCE }
        DOMFMA(A1, B1)
        if (ss + 4 < NSTG) { LDB(B1, ss + 4) LDA(A1, ss + 4) FENCE }
        DOMFMA(A2, B2)
        if (ss + 5 < NSTG) { LDB(B2, ss + 5) LDA(A2, ss + 5) FENCE }
    }

    #pragma unroll
    for (int ns = 0; ns < 2; ns++) {
        const int k = n0 + ns * 16 + cl;
        const float bk = bias[k];
        #pragma unroll
        for (int ms = 0; ms < 4; ms++) {
            #pragma unroll
            for (int r = 0; r < 4; r++) {
                int s = s0 + ms * 16 + quad * 4 + r;
                float v = acc[ms][ns][r] + bk;
                float e = __expf(2.f * v);
                float th = 1.f - 2.f / (e + 1.f); // tanh(v)
                xf[((size_t)b * S + s) * NK + k] = f2bf(th);
            }
        }
    }
}

// -------- MFMA attention: max-free softmax, bf16 U/F tables ----------------
// r9 post-mortem: three different schedules (r0/r6/r9) all pin at 66.5-69us,
// MfmaUtil 42-44 => shared-resource limit, not schedule. Per-CU budget at
// r9: MFMA 79.5k cyc (48%) but ds_read_b128 98k + LDS-writes 16k + conflicts
// 33k ~= 90% LDS-pipe busy. LDS pipe saturated: each wave read the whole
// 16KB tile for only 16 classes (1KB/class/tile).
// r(this): 32x32x16 MFMA — one b128 A-read covers 32 s-rows x 16k and pairs
// with 32 classes/wave => LDS reads per class HALVE; 32x32 pipe also faster
// (8.07 cyc/32k FLOP vs 2x4.85/2x16k). New budget: MFMA 66k, LDS ~65k.
// Operand safety: any consistent k-bijection on A and B cancels in the dot;
// M/N = lane&31 forced (32x16=512=64x8); C/D col=lane&31=class (m74), row
// reduced away. Schedule (triple buf, vmcnt(4), raw barrier) = r6/r9.
// r1: LDS staging load-bearing. r2: natural order has U/F XCD locality.
#define WAITVM4 asm volatile("s_waitcnt vmcnt(4)" ::: "memory")
#define WAITVM0 asm volatile("s_waitcnt vmcnt(0)" ::: "memory")
__global__ __launch_bounds__(256, 2) void attn_mfma(
    const unsigned short* __restrict__ xf, const unsigned short* __restrict__ Ub,
    const unsigned short* __restrict__ Fb, float* __restrict__ pl,
    float* __restrict__ pg)
{
    __shared__ unsigned short xsa[3 * 32 * NK];   // 3 x 16 KB
    const int b    = blockIdx.z;
    const int sp   = blockIdx.y;
    const int tid  = threadIdx.x;
    const int wv   = tid >> 6;
    const int lane = tid & 63;
    const int row  = lane & 31;                   // A s-row / B class row
    const int bh   = lane >> 5;                   // k-half selector
    const int c0   = blockIdx.x * 128 + wv * 32;  // 32 classes per wave
    const int wvu  = __builtin_amdgcn_readfirstlane(wv);

    // B tables: class = lane&31, k = bh*8 + kk*16 .. +8  (16 slices)
    bf16x8 uf[16], ff[16];
    {
        const unsigned short* up = Ub + (size_t)(c0 + row) * NK + bh * 8;
        const unsigned short* fp = Fb + (size_t)(c0 + row) * NK + bh * 8;
        #pragma unroll
        for (int kk = 0; kk < 16; kk++) {
            uf[kk] = *(const bf16x8*)(up + kk * 16);
            ff[kk] = *(const bf16x8*)(fp + kk * 16);
        }
    }

    const int sbeg = sp * (S / SSPLIT);
    const unsigned short* xb = xf + ((size_t)b * S + sbeg) * NK;

    // hoisted staging pointers (loop-invariant; only t*32*NK varies)
    const unsigned short* ssrc[4];
    unsigned short* sdst[4];
    #pragma unroll
    for (int j = 0; j < 4; j++) {
        int C = j * 256 + tid;
        int r = C >> 5, p = C & 31;
        int jl = p ^ (r & 7);
        ssrc[j] = xb + (size_t)r * NK + jl * 8;
        sdst[j] = xsa + j * 2048 + wvu * 512;
    }

    #define STAGE(bb, t)                                                      \
        {                                                                     \
            _Pragma("unroll")                                                 \
            for (int j = 0; j < 4; j++)                                       \
                GLOAD_LDS16(ssrc[j] + (t) * (32 * NK), sdst[j] + (bb) * 8192);\
        }

    STAGE(0, 0)
    STAGE(1, 1)

    const int sw = row & 7;
    float l = 0.f, G = 0.f;

    #pragma unroll
    for (int t = 0; t < NTILES; t++) {            // fully unrolled: buf static
        if (t + 1 < NTILES) { WAITVM4; } else { WAITVM0; }
        __builtin_amdgcn_s_barrier();
        if (t + 2 < NTILES) STAGE((t + 2) % 3, t + 2)

        const unsigned short* bs = xsa + (t % 3) * 8192 + row * NK;
        f32x16 sa = {}, ga = {};
        #pragma unroll
        for (int kk = 0; kk < 16; kk++) {
            int ch = 2 * kk + bh;                 // logical 16B chunk
            int ph = (ch & ~7) | ((ch & 7) ^ sw); // swizzled (low 3 bits)
            bf16x8 a = *(const bf16x8*)(bs + ph * 8);
            sa = __builtin_amdgcn_mfma_f32_32x32x16_bf16(a, uf[kk], sa, 0, 0, 0);
            ga = __builtin_amdgcn_mfma_f32_32x32x16_bf16(a, ff[kk], ga, 0, 0, 0);
        }

        // max-free softmax accumulation (rows fully in-register)
        #pragma unroll
        for (int r = 0; r < 16; r++) {
            float e = __builtin_amdgcn_exp2f(sa[r]);
            l += e;
            G += e * ga[r];
        }
    }

    // rows split across lane-halves only: one xor-32 finishes the s-reduce
    l += __shfl_xor(l, 32);
    G += __shfl_xor(G, 32);
    if (lane < 32) {
        size_t idx = ((size_t)b * SSPLIT + sp) * NC + c0 + lane;
        pl[idx] = l; pg[idx] = G;
    }
}

// -------- combine S-split partials + bias -> y [b][c] ----------------------
__global__ __launch_bounds__(256) void combine_kernel(
    const float* __restrict__ pl, const float* __restrict__ pg,
    const float* __restrict__ fb, float* __restrict__ out)
{
    int idx = blockIdx.x * 256 + threadIdx.x;     // over B*NC
    if (idx >= B * NC) return;
    int b = idx / NC, c = idx % NC;
    float l = 0.f, g = 0.f;
    #pragma unroll
    for (int sp = 0; sp < SSPLIT; sp++) {
        size_t i = ((size_t)b * SSPLIT + sp) * NC + c;
        l += pl[i];
        g += pg[i];
    }
    out[idx] = g / l + fb[c];
}

extern "C" void kernel_launch(void* const* d_in, const int* in_sizes, int n_in,
                              void* d_out, int out_size, void* d_ws, size_t ws_size,
                              hipStream_t stream) {
    const int*   text   = (const int*)  d_in[0];
    const float* emb    = (const float*)d_in[1];
    const float* conv_w = (const float*)d_in[2];
    const float* conv_b = (const float*)d_in[3];
    const float* U_w    = (const float*)d_in[4];
    const float* F_w    = (const float*)d_in[5];
    const float* f_b    = (const float*)d_in[6];
    float* out = (float*)d_out;

    char* ws = (char*)d_ws;
    unsigned short* xf  = (unsigned short*)ws; ws += (size_t)B * S * NK * 2;
    unsigned short* wtb = (unsigned short*)ws; ws += (size_t)KSZ * NK * D_MODEL * 2;
    unsigned short* Ub  = (unsigned short*)ws; ws += (size_t)NC * NK * 2;
    unsigned short* Fb  = (unsigned short*)ws; ws += (size_t)NC * NK * 2;
    float* pl = (float*)ws; ws += (size_t)SSPLIT * B * NC * 4;
    float* pg = (float*)ws; ws += (size_t)SSPLIT * B * NC * 4;

    prep_all<<<dim3((PREP_N + 255) / 256), 256, 0, stream>>>(conv_w, wtb, U_w, Ub, F_w, Fb);
    conv_mfma<<<dim3(B * S / CM), 512, 0, stream>>>(text, emb, wtb, conv_b, xf);
    attn_mfma<<<dim3(NC / 128, SSPLIT, B), 256, 0, stream>>>(xf, Ub, Fb, pl, pg);
    combine_kernel<<<dim3((B * NC + 255) / 256), 256, 0, stream>>>(pl, pg, f_b, out);
}